// Round 3
// baseline (97.552 us; speedup 1.0000x reference)
//
#include <hip/hip_runtime.h>
#include <hip/hip_bf16.h>

#define OUTN 11008
#define KDIM 4096
#define BDIM 32
#define NT   344          // OUTN / 32
#define WCOUNT 45088768   // OUTN * KDIM

typedef __bf16 bf16x8 __attribute__((ext_vector_type(8)));
typedef float f32x16 __attribute__((ext_vector_type(16)));

__device__ __forceinline__ ushort f2bf(float f) {
    // round-to-nearest-even f32 -> bf16
    unsigned u = __builtin_bit_cast(unsigned, f);
    u = (u + 0x7FFFu + ((u >> 16) & 1u)) >> 16;
    return (ushort)u;
}

__device__ __forceinline__ unsigned ternpair(float a, float b, float d) {
    // two ternary bf16 values packed into one u32 (little-endian k order)
    unsigned t0 = (a > d) ? 0x3F80u : ((a < -d) ? 0xBF80u : 0u);
    unsigned t1 = (b > d) ? 0x3F80u : ((b < -d) ? 0xBF80u : 0u);
    return t0 | (t1 << 16);
}

// ---------------- pass 1: sum(|W|) in f64 ----------------
__global__ __launch_bounds__(256) void abssum_k(const float4* __restrict__ w4,
                                                double* __restrict__ dsum) {
    const int tid = blockIdx.x * 256 + threadIdx.x;
    const int stride = gridDim.x * 256;
    double s = 0.0;
    for (int i = tid; i < WCOUNT / 4; i += stride) {
        float4 v = w4[i];
        s += (double)(fabsf(v.x) + fabsf(v.y)) + (double)(fabsf(v.z) + fabsf(v.w));
    }
    for (int off = 32; off; off >>= 1) s += __shfl_down(s, off);
    __shared__ double red[4];
    const int lane = threadIdx.x & 63, wv = threadIdx.x >> 6;
    if (lane == 0) red[wv] = s;
    __syncthreads();
    if (threadIdx.x == 0) {
        double t = red[0] + red[1] + red[2] + red[3];
        atomicAdd(dsum, t);
    }
}

// ---------------- pass 1.5: x f32 -> bf16, fragment-ordered [K/8][32][8] ----------------
__global__ __launch_bounds__(256) void xconv_k(const float* __restrict__ x,
                                               ushort* __restrict__ xb) {
    const int i4 = blockIdx.x * 256 + threadIdx.x;   // exactly 32768 float4s
    const int elem = i4 * 4;
    const int b = elem >> 12;          // / KDIM
    const int k = elem & (KDIM - 1);
    const float4 v = ((const float4*)x)[i4];
    ushort4 o;
    o.x = f2bf(v.x); o.y = f2bf(v.y); o.z = f2bf(v.z); o.w = f2bf(v.w);
    const int ofs = ((k >> 3) * 32 + b) * 8 + (k & 7);   // 8B aligned (k%4==0)
    *(ushort4*)(xb + ofs) = o;
}

// ---------------- pass 2: fused ternarize + MFMA GEMM ----------------
// one wave per block; 32x32 output tile over a K-chunk
template <bool XBF>
__global__ __launch_bounds__(64) void gemm_k(const float* __restrict__ W,
                                             const float* __restrict__ x,
                                             const ushort* __restrict__ xb,
                                             const double* __restrict__ dsum,
                                             float* __restrict__ dst,
                                             const float* __restrict__ alpha,
                                             const float* __restrict__ bias,
                                             int nks, int final_mode) {
    __shared__ uint4 sm[2][32 * 8];    // 2 bufs x 32 rows x 8 x 16B (64 bf16/row), XOR-swizzled
    const int l = threadIdx.x;
    const int tile = blockIdx.x % NT;
    const int ksid = blockIdx.x / NT;
    const int kchunk = KDIM / nks;
    const int niter = kchunk / 64;
    const int o0 = tile * 32;
    const int kt0 = ksid * kchunk;

    // delta in f64; comparison boundary as largest f32 <= delta_f64 so that
    // (w > delta_f64) == (w > dc) for all f32 w — matches an f64-delta reference.
    const double delta_d = 0.7 * (*dsum) * (1.0 / (double)WCOUNT);
    float dc = (float)delta_d;
    if ((double)dc > delta_d) {
        // next float toward -inf (delta is a positive normal): bits - 1
        dc = __builtin_bit_cast(float, __builtin_bit_cast(unsigned, dc) - 1u);
    }
    const float delta = dc;

    const int r = l >> 1, h = l & 1;   // staging: 2 lanes per W row, 128B each
    const float4* wp = (const float4*)(W + (size_t)(o0 + r) * KDIM + kt0 + h * 32);
    const uint4* xb4 = (const uint4*)xb;

    f32x16 acc;
#pragma unroll
    for (int i = 0; i < 16; ++i) acc[i] = 0.0f;

    float4 L[8];

    auto STAGE_LOAD = [&](int t) {
#pragma unroll
        for (int j = 0; j < 8; ++j) L[j] = wp[t * 16 + j];
    };
    auto TERN_WRITE = [&](int buf) {
#pragma unroll
        for (int j = 0; j < 4; ++j) {
            uint4 u;
            u.x = ternpair(L[2 * j].x,     L[2 * j].y,     delta);
            u.y = ternpair(L[2 * j].z,     L[2 * j].w,     delta);
            u.z = ternpair(L[2 * j + 1].x, L[2 * j + 1].y, delta);
            u.w = ternpair(L[2 * j + 1].z, L[2 * j + 1].w, delta);
            sm[buf][r * 8 + ((h * 4 + j) ^ (r & 7))] = u;
        }
    };
    auto COMPUTE = [&](int buf, int t) {
#pragma unroll
        for (int ks = 0; ks < 4; ++ks) {
            bf16x8 av;
            if constexpr (XBF) {
                const int k8 = (kt0 >> 3) + t * 8 + ks * 2 + (l >> 5);
                uint4 a4 = xb4[(size_t)k8 * 32 + (l & 31)];
                av = __builtin_bit_cast(bf16x8, a4);
            } else {
                const int kg = kt0 + t * 64 + ks * 16 + (l >> 5) * 8;
                const float4* xp = (const float4*)(x + (size_t)(l & 31) * KDIM + kg);
                float4 v0 = xp[0], v1 = xp[1];
                struct U { ushort s[8]; } uu;
                uu.s[0] = f2bf(v0.x); uu.s[1] = f2bf(v0.y);
                uu.s[2] = f2bf(v0.z); uu.s[3] = f2bf(v0.w);
                uu.s[4] = f2bf(v1.x); uu.s[5] = f2bf(v1.y);
                uu.s[6] = f2bf(v1.z); uu.s[7] = f2bf(v1.w);
                av = __builtin_bit_cast(bf16x8, uu);
            }
            const int row = l & 31;
            uint4 b4 = sm[buf][row * 8 + ((ks * 2 + (l >> 5)) ^ (row & 7))];
            bf16x8 bv = __builtin_bit_cast(bf16x8, b4);
            acc = __builtin_amdgcn_mfma_f32_32x32x16_bf16(av, bv, acc, 0, 0, 0);
        }
    };

    STAGE_LOAD(0);
    TERN_WRITE(0);
    __syncthreads();
    for (int t = 0; t < niter; ++t) {
        const int cur = t & 1;
        if (t + 1 < niter) STAGE_LOAD(t + 1);       // issue next-tile global loads early
        COMPUTE(cur, t);                            // MFMA hides the load latency
        if (t + 1 < niter) TERN_WRITE(cur ^ 1);     // vmcnt-wait lands here, after compute
        __syncthreads();
    }

    if (final_mode) {
        const float a = *alpha;
#pragma unroll
        for (int rg = 0; rg < 16; ++rg) {
            const int m = (rg & 3) + 8 * (rg >> 2) + 4 * (l >> 5);
            const int n = o0 + (l & 31);
            dst[(size_t)m * OUTN + n] = fmaf(a, acc[rg], bias[n]);
        }
    } else {
        float* po = dst + (size_t)ksid * (BDIM * OUTN);
#pragma unroll
        for (int rg = 0; rg < 16; ++rg) {
            const int m = (rg & 3) + 8 * (rg >> 2) + 4 * (l >> 5);
            po[(size_t)m * OUTN + o0 + (l & 31)] = acc[rg];
        }
    }
}

// ---------------- pass 3: combine K-split partials + alpha + bias ----------------
__global__ __launch_bounds__(256) void combine_k(const float4* __restrict__ part,
                                                 const float* __restrict__ alpha,
                                                 const float4* __restrict__ bias4,
                                                 float4* __restrict__ out4,
                                                 int nks) {
    const int i = blockIdx.x * 256 + threadIdx.x;   // exactly 88064
    const float a = *alpha;
    float4 s = part[i];
    for (int k = 1; k < nks; ++k) {
        float4 p = part[i + (size_t)k * (BDIM * OUTN / 4)];
        s.x += p.x; s.y += p.y; s.z += p.z; s.w += p.w;
    }
    const float4 b = bias4[i % (OUTN / 4)];
    float4 o;
    o.x = fmaf(a, s.x, b.x); o.y = fmaf(a, s.y, b.y);
    o.z = fmaf(a, s.z, b.z); o.w = fmaf(a, s.w, b.w);
    out4[i] = o;
}

extern "C" void kernel_launch(void* const* d_in, const int* in_sizes, int n_in,
                              void* d_out, int out_size, void* d_ws, size_t ws_size,
                              hipStream_t stream) {
    const float* x     = (const float*)d_in[0];
    const float* W     = (const float*)d_in[1];
    const float* alpha = (const float*)d_in[2];
    const float* bias  = (const float*)d_in[3];
    float* out = (float*)d_out;

    double* dsum = (double*)d_ws;
    const size_t XBF_OFF = 1024;
    const size_t XBF_SZ  = (size_t)BDIM * KDIM * 2;         // 256 KiB
    const size_t PART_OFF = XBF_OFF + XBF_SZ;
    const size_t PART_SZ4 = 4 * (size_t)BDIM * OUTN * 4;    // 5.5 MiB for KS=4

    const bool use_xbf = ws_size >= XBF_OFF + XBF_SZ;
    const int nks = (use_xbf && ws_size >= PART_OFF + PART_SZ4) ? 4 : 1;

    (void)hipMemsetAsync(d_ws, 0, 64, stream);              // zero the f64 accumulator
    abssum_k<<<1024, 256, 0, stream>>>((const float4*)W, dsum);

    ushort* xb = (ushort*)((char*)d_ws + XBF_OFF);
    if (use_xbf) xconv_k<<<128, 256, 0, stream>>>(x, xb);

    if (nks == 4) {
        float* part = (float*)((char*)d_ws + PART_OFF);
        gemm_k<true><<<NT * 4, 64, 0, stream>>>(W, x, xb, dsum, part, alpha, bias, 4, 0);
        combine_k<<<344, 256, 0, stream>>>((const float4*)part, alpha,
                                           (const float4*)bias, (float4*)out, 4);
    } else if (use_xbf) {
        gemm_k<true><<<NT, 64, 0, stream>>>(W, x, xb, dsum, out, alpha, bias, 1, 1);
    } else {
        gemm_k<false><<<NT, 64, 0, stream>>>(W, x, nullptr, dsum, out, alpha, bias, 1, 1);
    }
}

// Round 4
// 84.502 us; speedup vs baseline: 1.1544x; 1.1544x over previous
//
#include <hip/hip_runtime.h>
#include <hip/hip_bf16.h>

#define OUTN 11008
#define KDIM 4096
#define BDIM 32
#define NT   344          // OUTN / 32
#define WCOUNT 45088768   // OUTN * KDIM

typedef __bf16 bf16x8 __attribute__((ext_vector_type(8)));
typedef float f32x16 __attribute__((ext_vector_type(16)));

__device__ __forceinline__ ushort f2bf(float f) {
    unsigned u = __builtin_bit_cast(unsigned, f);
    u = (u + 0x7FFFu + ((u >> 16) & 1u)) >> 16;
    return (ushort)u;
}

// ternary as f32 bits: sign(w)*1.0f if |w|>d else 0
__device__ __forceinline__ unsigned tern1(float w, float d) {
    unsigned b = __builtin_bit_cast(unsigned, w);
    unsigned s = (b & 0x80000000u) | 0x3F800000u;   // v_and_or_b32
    return (__builtin_fabsf(w) > d) ? s : 0u;       // cmp with |.| modifier + cndmask
}
// pack two ternary values as 2 bf16 (a -> low 16, b -> high 16)
__device__ __forceinline__ unsigned ternpack(float a, float b, float d) {
    return __builtin_amdgcn_perm(tern1(b, d), tern1(a, d), 0x07060302u);
}

// ---------------- pass 1: sum(|W|) in f64 ----------------
__global__ __launch_bounds__(256) void abssum_k(const float4* __restrict__ w4,
                                                double* __restrict__ dsum) {
    const int tid = blockIdx.x * 256 + threadIdx.x;
    const int stride = gridDim.x * 256;
    double s = 0.0;
    for (int i = tid; i < WCOUNT / 4; i += stride) {
        float4 v = w4[i];
        s += (double)(fabsf(v.x) + fabsf(v.y)) + (double)(fabsf(v.z) + fabsf(v.w));
    }
    for (int off = 32; off; off >>= 1) s += __shfl_down(s, off);
    __shared__ double red[4];
    const int lane = threadIdx.x & 63, wv = threadIdx.x >> 6;
    if (lane == 0) red[wv] = s;
    __syncthreads();
    if (threadIdx.x == 0) {
        double t = red[0] + red[1] + red[2] + red[3];
        atomicAdd(dsum, t);
    }
}

// ---------------- pass 0: x f32 -> bf16, fragment-ordered [K/8][32][8] ----------------
__global__ __launch_bounds__(256) void xconv_k(const float* __restrict__ x,
                                               ushort* __restrict__ xb) {
    const int i4 = blockIdx.x * 256 + threadIdx.x;   // exactly 32768 float4s
    const int elem = i4 * 4;
    const int b = elem >> 12;          // / KDIM
    const int k = elem & (KDIM - 1);
    const float4 v = ((const float4*)x)[i4];
    ushort4 o;
    o.x = f2bf(v.x); o.y = f2bf(v.y); o.z = f2bf(v.z); o.w = f2bf(v.w);
    const int ofs = ((k >> 3) * 32 + b) * 8 + (k & 7);
    *(ushort4*)(xb + ofs) = o;
}

// ---------------- pass 2: fused ternarize + MFMA GEMM, register-only ----------------
// one wave per block; 32x32 output tile over a K-chunk; W loaded directly in
// B-fragment layout (lane = W row l&31, k-offset (l>>5)*8), ternarized in regs.
template <int NKS, bool XBF>
__global__ __launch_bounds__(64) void gemm_k(const float* __restrict__ W,
                                             const float* __restrict__ x,
                                             const ushort* __restrict__ xb,
                                             const double* __restrict__ dsum,
                                             float* __restrict__ dst,
                                             const float* __restrict__ alpha,
                                             const float* __restrict__ bias,
                                             int final_mode) {
    constexpr int KCH = KDIM / NKS;
    constexpr int NSTEP = KCH / 16;
    const int l = threadIdx.x;
    const int tile = blockIdx.x % NT;
    const int ksid = blockIdx.x / NT;
    const int o0 = tile * 32;
    const int kt0 = ksid * KCH;

    // delta boundary: largest f32 <= delta_f64 so (w > delta_f64) == (w > delta)
    const double delta_d = 0.7 * (*dsum) * (1.0 / (double)WCOUNT);
    float dc = (float)delta_d;
    if ((double)dc > delta_d)
        dc = __builtin_bit_cast(float, __builtin_bit_cast(unsigned, dc) - 1u);
    const float delta = dc;

    const int row = l & 31, half = l >> 5;
    const float4* wp = (const float4*)(W + (size_t)(o0 + row) * KDIM + kt0 + half * 8);
    const uint4* xa = (const uint4*)xb + ((size_t)(kt0 >> 3) + half) * 32 + row;
    const float4* xp = (const float4*)(x + (size_t)row * KDIM + kt0 + half * 8);

    f32x16 acc;
#pragma unroll
    for (int i = 0; i < 16; ++i) acc[i] = 0.0f;

    // prefetch step 0
    float4 w0 = wp[0], w1 = wp[1];
    uint4 a0;
    float4 xf0, xf1;
    if constexpr (XBF) a0 = xa[0];
    else { xf0 = xp[0]; xf1 = xp[1]; }

#pragma unroll 4
    for (int s = 0; s < NSTEP; ++s) {
        float4 nw0, nw1; uint4 na; float4 nx0, nx1;
        if (s + 1 < NSTEP) {                 // distance-1 register prefetch
            nw0 = wp[(s + 1) * 4];
            nw1 = wp[(s + 1) * 4 + 1];
            if constexpr (XBF) na = xa[(size_t)(s + 1) * 64];
            else { nx0 = xp[(s + 1) * 4]; nx1 = xp[(s + 1) * 4 + 1]; }
        }
        uint4 bb;
        bb.x = ternpack(w0.x, w0.y, delta);
        bb.y = ternpack(w0.z, w0.w, delta);
        bb.z = ternpack(w1.x, w1.y, delta);
        bb.w = ternpack(w1.z, w1.w, delta);
        bf16x8 av;
        if constexpr (XBF) {
            av = __builtin_bit_cast(bf16x8, a0);
        } else {
            struct U { ushort s[8]; } uu;
            uu.s[0] = f2bf(xf0.x); uu.s[1] = f2bf(xf0.y);
            uu.s[2] = f2bf(xf0.z); uu.s[3] = f2bf(xf0.w);
            uu.s[4] = f2bf(xf1.x); uu.s[5] = f2bf(xf1.y);
            uu.s[6] = f2bf(xf1.z); uu.s[7] = f2bf(xf1.w);
            av = __builtin_bit_cast(bf16x8, uu);
        }
        acc = __builtin_amdgcn_mfma_f32_32x32x16_bf16(
                  av, __builtin_bit_cast(bf16x8, bb), acc, 0, 0, 0);
        w0 = nw0; w1 = nw1;
        if constexpr (XBF) a0 = na; else { xf0 = nx0; xf1 = nx1; }
    }

    if (final_mode) {
        const float a = *alpha;
#pragma unroll
        for (int rg = 0; rg < 16; ++rg) {
            const int m = (rg & 3) + 8 * (rg >> 2) + 4 * half;
            const int n = o0 + row;
            dst[(size_t)m * OUTN + n] = fmaf(a, acc[rg], bias[n]);
        }
    } else {
        float* po = dst + (size_t)ksid * (BDIM * OUTN);
#pragma unroll
        for (int rg = 0; rg < 16; ++rg) {
            const int m = (rg & 3) + 8 * (rg >> 2) + 4 * half;
            po[(size_t)m * OUTN + o0 + row] = acc[rg];
        }
    }
}

// ---------------- pass 3: combine K-split partials + alpha + bias ----------------
__global__ __launch_bounds__(256) void combine_k(const float4* __restrict__ part,
                                                 const float* __restrict__ alpha,
                                                 const float4* __restrict__ bias4,
                                                 float4* __restrict__ out4,
                                                 int nks) {
    const int i = blockIdx.x * 256 + threadIdx.x;   // exactly 88064
    const float a = *alpha;
    float4 s = part[i];
    for (int k = 1; k < nks; ++k) {
        float4 p = part[i + (size_t)k * (BDIM * OUTN / 4)];
        s.x += p.x; s.y += p.y; s.z += p.z; s.w += p.w;
    }
    const float4 b = bias4[i % (OUTN / 4)];
    float4 o;
    o.x = fmaf(a, s.x, b.x); o.y = fmaf(a, s.y, b.y);
    o.z = fmaf(a, s.z, b.z); o.w = fmaf(a, s.w, b.w);
    out4[i] = o;
}

extern "C" void kernel_launch(void* const* d_in, const int* in_sizes, int n_in,
                              void* d_out, int out_size, void* d_ws, size_t ws_size,
                              hipStream_t stream) {
    const float* x     = (const float*)d_in[0];
    const float* W     = (const float*)d_in[1];
    const float* alpha = (const float*)d_in[2];
    const float* bias  = (const float*)d_in[3];
    float* out = (float*)d_out;

    double* dsum = (double*)d_ws;
    const size_t XBF_OFF = 1024;
    const size_t XBF_SZ  = (size_t)BDIM * KDIM * 2;            // 256 KiB
    const size_t PART_OFF = XBF_OFF + XBF_SZ;
    const size_t PART_SZ  = 8 * (size_t)BDIM * OUTN * 4;       // 11.3 MiB, KS=8

    const bool use_xbf = ws_size >= XBF_OFF + XBF_SZ;
    const bool use_ks  = use_xbf && ws_size >= PART_OFF + PART_SZ;

    (void)hipMemsetAsync(d_ws, 0, 64, stream);                 // zero the f64 accumulator

    ushort* xb = (ushort*)((char*)d_ws + XBF_OFF);
    if (use_xbf) xconv_k<<<128, 256, 0, stream>>>(x, xb);

    // abssum last before gemm: leaves W freshest in L3 for the re-read
    abssum_k<<<1024, 256, 0, stream>>>((const float4*)W, dsum);

    if (use_ks) {
        float* part = (float*)((char*)d_ws + PART_OFF);
        gemm_k<8, true><<<NT * 8, 64, 0, stream>>>(W, x, xb, dsum, part, alpha, bias, 0);
        combine_k<<<344, 256, 0, stream>>>((const float4*)part, alpha,
                                           (const float4*)bias, (float4*)out, 8);
    } else if (use_xbf) {
        gemm_k<1, true><<<NT, 64, 0, stream>>>(W, x, xb, dsum, out, alpha, bias, 1);
    } else {
        gemm_k<1, false><<<NT, 64, 0, stream>>>(W, x, nullptr, dsum, out, alpha, bias, 1);
    }
}